// Round 3
// baseline (495.464 us; speedup 1.0000x reference)
//
#include <hip/hip_runtime.h>
#include <hip/hip_bf16.h>

typedef unsigned short u16;
typedef _Float16 h16;
typedef h16 h16x8 __attribute__((ext_vector_type(8)));
typedef h16 h16x4 __attribute__((ext_vector_type(4)));
typedef float f32x4 __attribute__((ext_vector_type(4)));

#define S_LEN 2048
#define HID   2048
#define QLR   1536
#define KVLR  512
#define ROPE_D 64
#define NHEAD 16
#define QHD   192
#define NOPE  128
#define VDIM  128
#define NKV_PAD 640
#define SCALE 0.07216878364870322f   // 192^-0.5

__device__ __forceinline__ void gld16(const h16* g, h16* l){
  __builtin_amdgcn_global_load_lds((__attribute__((address_space(1))) const void*)g,
                                   (__attribute__((address_space(3))) void*)l, 16, 0, 0);
}

// ---------- fp32 -> fp16 elementwise ----------
__global__ __launch_bounds__(256) void k_cvt(const float* __restrict__ in, h16* __restrict__ out, int n4){
  int i = blockIdx.x * 256 + threadIdx.x;
  if (i < n4){
    float4 v = ((const float4*)in)[i];
    h16x4 o = { (h16)v.x, (h16)v.y, (h16)v.z, (h16)v.w };
    ((h16x4*)out)[i] = o;
  }
}

// ---------- fp32 KxN -> fp16 NxK (transpose, for B^T GEMM operand) ----------
__global__ __launch_bounds__(256) void k_tc(const float* __restrict__ W, h16* __restrict__ WT, int K, int N){
  __shared__ float t[32][33];
  int k0 = blockIdx.y * 32, n0 = blockIdx.x * 32;
  int tid = threadIdx.x;
  int r  = tid >> 3, c4 = (tid & 7) * 4;
  float4 v = *(const float4*)(W + (size_t)(k0 + r) * N + n0 + c4);
  t[r][c4] = v.x; t[r][c4+1] = v.y; t[r][c4+2] = v.z; t[r][c4+3] = v.w;
  __syncthreads();
  h16x4 o = { (h16)t[c4][r], (h16)t[c4+1][r], (h16)t[c4+2][r], (h16)t[c4+3][r] };
  *(h16x4*)(WT + (size_t)(n0 + r) * K + k0 + c4) = o;
}

// ---------- GEMM: A (MxK row-major f16), B^T (NxK row-major f16) -> C (MxN) ----------
// m97-style: 128x128 tile, BK=32, 4 waves 2x2, each wave 4x4 of 16x16x32 MFMA.
template<bool OF32>
__global__ __launch_bounds__(256) void k_gemm(const h16* __restrict__ A, const h16* __restrict__ B,
                                              void* __restrict__ Cv, int M, int N, int K){
  __shared__ __attribute__((aligned(16))) h16 As[128 * 32];
  __shared__ __attribute__((aligned(16))) h16 Bs[128 * 32];
  const int tid = threadIdx.x;
  const int m0 = blockIdx.y * 128, n0 = blockIdx.x * 128;
  const int lane = tid & 63, quad = lane >> 4, lr = lane & 15;
  const int wid = tid >> 6;
  const int wr = (wid >> 1) * 64, wc = (wid & 1) * 64;
  f32x4 acc[4][4] = {};
  const int sr = tid >> 2, scc = (tid & 3) * 8;
  const h16* Ag = A + (size_t)(m0 + sr) * K + scc;
  const h16* Bg = B + (size_t)(n0 + sr) * K + scc;
  for (int kt = 0; kt < K; kt += 32){
    gld16(Ag + kt,                 &As[tid * 8]);
    gld16(Ag + (size_t)64*K + kt,  &As[2048 + tid * 8]);
    gld16(Bg + kt,                 &Bs[tid * 8]);
    gld16(Bg + (size_t)64*K + kt,  &Bs[2048 + tid * 8]);
    __syncthreads();
    h16x8 af[4], bfr[4];
#pragma unroll
    for (int r = 0; r < 4; r++) af[r]  = *(const h16x8*)&As[(wr + r*16 + lr) * 32 + quad * 8];
#pragma unroll
    for (int c = 0; c < 4; c++) bfr[c] = *(const h16x8*)&Bs[(wc + c*16 + lr) * 32 + quad * 8];
#pragma unroll
    for (int r = 0; r < 4; r++)
#pragma unroll
      for (int c = 0; c < 4; c++)
        acc[r][c] = __builtin_amdgcn_mfma_f32_16x16x32_f16(af[r], bfr[c], acc[r][c], 0, 0, 0);
    __syncthreads();
  }
  // C/D layout: col = lane&15, row = quad*4 + reg
#pragma unroll
  for (int r = 0; r < 4; r++)
#pragma unroll
    for (int c = 0; c < 4; c++){
      int row = m0 + wr + r*16 + quad*4;
      int col = n0 + wc + c*16 + lr;
#pragma unroll
      for (int i = 0; i < 4; i++){
        float val = acc[r][c][i];
        if (OF32) ((float*)Cv)[(size_t)(row + i) * N + col] = val;
        else      ((h16*)Cv)[(size_t)(row + i) * N + col] = (h16)val;
      }
    }
}

// ---------- RMSNorm (q 1536, kv 512) + k_pe RoPE ----------
__global__ __launch_bounds__(256) void k_norm(const h16* __restrict__ C1, const h16* __restrict__ Ckv,
      const float* __restrict__ qw, const float* __restrict__ kw, const int* __restrict__ pos_ids,
      h16* __restrict__ qln, h16* __restrict__ kvln, h16* __restrict__ kpe){
  const int s = blockIdx.x, tid = threadIdx.x;
  __shared__ float red[8];
  const h16* c1 = C1 + (size_t)s * QLR;
  float v[6]; float ss = 0.f;
#pragma unroll
  for (int i = 0; i < 6; i++){ v[i] = (float)c1[tid + i*256]; ss += v[i]*v[i]; }
  for (int off = 32; off > 0; off >>= 1) ss += __shfl_down(ss, off);
  if ((tid & 63) == 0) red[tid >> 6] = ss;
  __syncthreads();
  float rq = rsqrtf((red[0]+red[1]+red[2]+red[3]) / (float)QLR + 1e-6f);
#pragma unroll
  for (int i = 0; i < 6; i++)
    qln[(size_t)s * QLR + tid + i*256] = (h16)(qw[tid + i*256] * v[i] * rq);

  const h16* ck = Ckv + (size_t)s * NKV_PAD;
  float w0 = (float)ck[tid], w1 = (float)ck[tid + 256];
  float ss2 = w0*w0 + w1*w1;
  for (int off = 32; off > 0; off >>= 1) ss2 += __shfl_down(ss2, off);
  if ((tid & 63) == 0) red[4 + (tid >> 6)] = ss2;
  __syncthreads();
  float rk = rsqrtf((red[4]+red[5]+red[6]+red[7]) / (float)KVLR + 1e-6f);
  kvln[(size_t)s * KVLR + tid]       = (h16)(kw[tid] * w0 * rk);
  kvln[(size_t)s * KVLR + tid + 256] = (h16)(kw[tid + 256] * w1 * rk);

  if (tid < 32){
    int d = tid;
    float x = (float)ck[KVLR + 2*d];
    float y = (float)ck[KVLR + 2*d + 1];
    float p = (float)pos_ids[s];
    float freq = exp2f(-0.4152410118609203f * (float)d);  // 10000^(-d/32)
    float a = p * freq;
    float cs = cosf(a), sn = sinf(a);
    kpe[(size_t)s * ROPE_D + d]      = (h16)(x*cs - y*sn);
    kpe[(size_t)s * ROPE_D + 32 + d] = (h16)(y*cs + x*sn);
  }
}

// ---------- assemble per-head Q (prescaled), K=[k_nope|k_pe], V^T ----------
__global__ __launch_bounds__(256) void k_asm(const h16* __restrict__ Qm, const h16* __restrict__ KVm,
      const h16* __restrict__ kpe, const int* __restrict__ pos_ids,
      h16* __restrict__ Qh, h16* __restrict__ Kh, h16* __restrict__ VT){
  const int s = blockIdx.x, tid = threadIdx.x;
  float cs = 0.f, sn = 0.f;
  if (tid >= 128 && tid < 160){
    int d = tid - 128;
    float freq = exp2f(-0.4152410118609203f * (float)d);
    float a = (float)pos_ids[s] * freq;
    cs = cosf(a); sn = sinf(a);
  }
  for (int h = 0; h < NHEAD; ++h){
    const h16* qrow  = Qm  + (size_t)s * (NHEAD*QHD) + h*QHD;
    const h16* kvrow = KVm + (size_t)s * (NHEAD*(NOPE+VDIM)) + h*(NOPE+VDIM);
    h16* qh = Qh + ((size_t)h * S_LEN + s) * QHD;
    h16* kh = Kh + ((size_t)h * S_LEN + s) * QHD;
    if (tid < 128){
      qh[tid] = (h16)((float)qrow[tid] * SCALE);
      kh[tid] = kvrow[tid];
      VT[((size_t)h * VDIM + tid) * S_LEN + s] = kvrow[NOPE + tid];
    } else if (tid < 160){
      int d = tid - 128;
      float x = (float)qrow[NOPE + 2*d];
      float y = (float)qrow[NOPE + 2*d + 1];
      qh[NOPE + d]      = (h16)((x*cs - y*sn) * SCALE);
      qh[NOPE + 32 + d] = (h16)((y*cs + x*sn) * SCALE);
      kh[NOPE + d]      = kpe[(size_t)s * ROPE_D + d];
      kh[NOPE + 32 + d] = kpe[(size_t)s * ROPE_D + 32 + d];
    }
  }
}

// ---------- causal flash attention: BM=128 (4 waves x 32 rows), BKV=64 ----------
__global__ __launch_bounds__(256) void k_flash(const h16* __restrict__ Qh, const h16* __restrict__ Kh,
      const h16* __restrict__ VT, h16* __restrict__ O){
  const int qi = blockIdx.x, h = blockIdx.y;
  const int m0 = qi * 128;
  __shared__ __attribute__((aligned(16))) h16 smem[28672]; // 56KB
  h16* Ksm = smem;            // [64][192]
  h16* Vsm = smem + 12288;    // [128][64]  (V^T tile: rows=dv, cols=kv)
  h16* Psm = smem + 20480;    // 4 waves x [32][64]
  const int tid = threadIdx.x, wid = tid >> 6, lane = tid & 63, quad = lane >> 4, lr = lane & 15;

  // stage Q tile (contiguous 128x192) then snapshot fragments into regs
  const h16* Qg = Qh + ((size_t)h * S_LEN + m0) * QHD;
#pragma unroll
  for (int i = 0; i < 12; i++) gld16(Qg + i*2048 + tid*8, &smem[i*2048 + tid*8]);
  __syncthreads();
  h16x8 qf[2][6];
#pragma unroll
  for (int rt = 0; rt < 2; rt++)
#pragma unroll
    for (int ks = 0; ks < 6; ks++)
      qf[rt][ks] = *(const h16x8*)&smem[(wid*32 + rt*16 + lr) * QHD + ks*32 + quad*8];
  __syncthreads();

  float mst[2][4], lst[2][4];
  f32x4 oacc[2][8] = {};
#pragma unroll
  for (int rt = 0; rt < 2; rt++)
#pragma unroll
    for (int i = 0; i < 4; i++){ mst[rt][i] = -1e30f; lst[rt][i] = 0.f; }

  const int jmax = 2*qi + 1;
  for (int j = 0; j <= jmax; ++j){
    const h16* Kg = Kh + ((size_t)h * S_LEN + j*64) * QHD;
#pragma unroll
    for (int i = 0; i < 6; i++) gld16(Kg + i*2048 + tid*8, &Ksm[i*2048 + tid*8]);
    const h16* Vg = VT + (size_t)h * VDIM * S_LEN + (size_t)j * 64;
#pragma unroll
    for (int i = 0; i < 4; i++){
      int r = i*32 + (tid >> 3), c = (tid & 7) * 8;
      gld16(Vg + (size_t)r * S_LEN + c, &Vsm[r*64 + c]);
    }
    __syncthreads();

    f32x4 sc[2][4] = {};
#pragma unroll
    for (int ks = 0; ks < 6; ks++)
#pragma unroll
      for (int ct = 0; ct < 4; ct++){
        h16x8 kf = *(const h16x8*)&Ksm[(ct*16 + lr) * QHD + ks*32 + quad*8];
        sc[0][ct] = __builtin_amdgcn_mfma_f32_16x16x32_f16(qf[0][ks], kf, sc[0][ct], 0,0,0);
        sc[1][ct] = __builtin_amdgcn_mfma_f32_16x16x32_f16(qf[1][ks], kf, sc[1][ct], 0,0,0);
      }

    if (j >= 2*qi){
#pragma unroll
      for (int rt = 0; rt < 2; rt++)
#pragma unroll
        for (int ct = 0; ct < 4; ct++){
          int kcol = j*64 + ct*16 + lr;
#pragma unroll
          for (int i = 0; i < 4; i++){
            int qrow = m0 + wid*32 + rt*16 + quad*4 + i;
            if (kcol > qrow) sc[rt][ct][i] = -1e30f;
          }
        }
    }

#pragma unroll
    for (int rt = 0; rt < 2; rt++){
      float al[4], rs[4];
#pragma unroll
      for (int i = 0; i < 4; i++){
        float m = fmaxf(fmaxf(sc[rt][0][i], sc[rt][1][i]), fmaxf(sc[rt][2][i], sc[rt][3][i]));
#pragma unroll
        for (int off = 1; off < 16; off <<= 1) m = fmaxf(m, __shfl_xor(m, off));
        float mn = fmaxf(mst[rt][i], m);
        al[i] = __expf(mst[rt][i] - mn);
        mst[rt][i] = mn;
        rs[i] = 0.f;
      }
#pragma unroll
      for (int ct = 0; ct < 4; ct++)
#pragma unroll
        for (int i = 0; i < 4; i++){
          float pv = __expf(sc[rt][ct][i] - mst[rt][i]);
          rs[i] += pv;
          Psm[wid*2048 + (rt*16 + quad*4 + i)*64 + ct*16 + lr] = (h16)pv;
        }
#pragma unroll
      for (int i = 0; i < 4; i++){
        float r = rs[i];
#pragma unroll
        for (int off = 1; off < 16; off <<= 1) r += __shfl_xor(r, off);
        lst[rt][i] = lst[rt][i]*al[i] + r;
#pragma unroll
        for (int oc = 0; oc < 8; oc++) oacc[rt][oc][i] *= al[i];
      }
    }
    __syncthreads();   // P writes visible (C-layout -> A-layout via LDS)

#pragma unroll
    for (int ks2 = 0; ks2 < 2; ks2++){
      h16x8 pf0 = *(const h16x8*)&Psm[wid*2048 + (lr)*64      + ks2*32 + quad*8];
      h16x8 pf1 = *(const h16x8*)&Psm[wid*2048 + (16 + lr)*64 + ks2*32 + quad*8];
#pragma unroll
      for (int oc = 0; oc < 8; oc++){
        h16x8 vf = *(const h16x8*)&Vsm[(oc*16 + lr)*64 + ks2*32 + quad*8];
        oacc[0][oc] = __builtin_amdgcn_mfma_f32_16x16x32_f16(pf0, vf, oacc[0][oc], 0,0,0);
        oacc[1][oc] = __builtin_amdgcn_mfma_f32_16x16x32_f16(pf1, vf, oacc[1][oc], 0,0,0);
      }
    }
    __syncthreads();   // protect K/V/P tiles before next staging
  }

#pragma unroll
  for (int rt = 0; rt < 2; rt++){
    float inv[4];
#pragma unroll
    for (int i = 0; i < 4; i++) inv[i] = 1.f / lst[rt][i];
#pragma unroll
    for (int oc = 0; oc < 8; oc++){
      int col = h*VDIM + oc*16 + lr;
#pragma unroll
      for (int i = 0; i < 4; i++){
        int row = m0 + wid*32 + rt*16 + quad*4 + i;
        O[(size_t)row * (NHEAD*VDIM) + col] = (h16)(oacc[rt][oc][i] * inv[i]);
      }
    }
  }
}

extern "C" void kernel_launch(void* const* d_in, const int* in_sizes, int n_in,
                              void* d_out, int out_size, void* d_ws, size_t ws_size,
                              hipStream_t stream){
  const float* hidden = (const float*)d_in[0];
  const int*   pos    = (const int*)  d_in[1];
  const float* Wqa    = (const float*)d_in[2];
  const float* qaw    = (const float*)d_in[3];
  const float* Wqb    = (const float*)d_in[4];
  const float* Wkva   = (const float*)d_in[5];
  const float* kvw    = (const float*)d_in[6];
  const float* Wkvb   = (const float*)d_in[7];
  const float* Wo     = (const float*)d_in[8];

  h16* ws = (h16*)d_ws;
  size_t off = 0;
  auto take = [&](size_t n){ h16* p = ws + off; off += n; return p; };
  h16* hb    = take(2048ull * 2048);
  h16* WqaT  = take(1536ull * 2048);
  h16* WkvaT = take(640ull  * 2048);   // 576 real rows + 64 pad rows (unused cols)
  h16* WqbT  = take(3072ull * 1536);
  h16* WkvbT = take(4096ull * 512);
  h16* WoT   = take(2048ull * 2048);
  h16* C1    = take(2048ull * 1536);
  h16* Ckv   = take(2048ull * 640);
  h16* qln   = take(2048ull * 1536);
  h16* kvln  = take(2048ull * 512);
  h16* kpe   = take(2048ull * 64);
  h16* Qm    = take(2048ull * 3072);
  h16* KVm   = take(2048ull * 4096);
  h16* Qh    = take(16ull * 2048 * 192);
  h16* Kh    = take(16ull * 2048 * 192);
  h16* VT    = take(16ull * 128 * 2048);
  h16* Ob    = hb;  // hb dead after the first two GEMMs; reuse for attention output

  k_cvt<<<4096, 256, 0, stream>>>(hidden, hb, 1048576);
  k_tc<<<dim3(1536/32, 2048/32), 256, 0, stream>>>(Wqa,  WqaT,  2048, 1536);
  k_tc<<<dim3( 576/32, 2048/32), 256, 0, stream>>>(Wkva, WkvaT, 2048, 576);
  k_tc<<<dim3(3072/32, 1536/32), 256, 0, stream>>>(Wqb,  WqbT,  1536, 3072);
  k_tc<<<dim3(4096/32,  512/32), 256, 0, stream>>>(Wkvb, WkvbT, 512,  4096);
  k_tc<<<dim3(2048/32, 2048/32), 256, 0, stream>>>(Wo,   WoT,   2048, 2048);

  k_gemm<false><<<dim3(12, 16), 256, 0, stream>>>(hb, WqaT,  C1,  2048, 1536, 2048);
  k_gemm<false><<<dim3( 5, 16), 256, 0, stream>>>(hb, WkvaT, Ckv, 2048, 640,  2048);
  k_norm<<<2048, 256, 0, stream>>>(C1, Ckv, qaw, kvw, pos, qln, kvln, kpe);
  k_gemm<false><<<dim3(24, 16), 256, 0, stream>>>(qln,  WqbT,  Qm,  2048, 3072, 1536);
  k_gemm<false><<<dim3(32, 16), 256, 0, stream>>>(kvln, WkvbT, KVm, 2048, 4096, 512);
  k_asm<<<2048, 256, 0, stream>>>(Qm, KVm, kpe, pos, Qh, Kh, VT);
  k_flash<<<dim3(16, 16), 256, 0, stream>>>(Qh, Kh, VT, Ob);
  k_gemm<true><<<dim3(16, 16), 256, 0, stream>>>(Ob, WoT, d_out, 2048, 2048, 2048);
}